// Round 6
// baseline (16101.141 us; speedup 1.0000x reference)
//
#include <hip/hip_runtime.h>
#include <math.h>

// EchoStateNetwork: B=32, S=4096, I=64, R=1024, O=8, fp32.
// 8 groups x 32 WGs by blockIdx; each group advances 4 chains.
// Each WG: 32 rows x 1024 cols of W_res held in 64 AGPRs/thread via
// explicit v_accvgpr_write/read (immune to the scratch-spill cost model
// that hit rounds 1/2/5). Static LDS ~83KB -> compile-time 1 WG/CU ->
// 2 waves/EU -> 256-reg combined budget AND guaranteed co-residency of
// all 256 WGs (grid == CU count). Cross-WG exchange: RELAXED agent-scope
// atomics (proven round 3/5); ordering via the vmcnt(0) drain of
// __syncthreads before the arrival add. Arrive-early/wait-late barrier
// with shadow work (x[t+1] prefetch + rotating local output reduction).

#define NS 4096
#define NI 64
#define NR 1024
#define NO 8
#define NB 32
#define NGRP 8
#define GPP 32      // WGs per group
#define CPG 4       // chains per group
#define WROWS 32    // W_res rows per WG
#define NT 512
#define WOC (NI + NR + 1)   // padded W_out row stride in LDS

#define ATLF(p)   __hip_atomic_load((p), __ATOMIC_RELAXED, __HIP_MEMORY_SCOPE_AGENT)
#define ATSF(p,v) __hip_atomic_store((p), (v), __ATOMIC_RELAXED, __HIP_MEMORY_SCOPE_AGENT)
#define ATLU(p)   __hip_atomic_load((p), __ATOMIC_RELAXED, __HIP_MEMORY_SCOPE_AGENT)

__global__ void init_cnt_kernel(unsigned int* cnt) {
  cnt[threadIdx.x] = 0u;   // zero 4 KB of barrier counters
}

__global__ __launch_bounds__(NT)
__attribute__((amdgpu_waves_per_eu(2, 2)))
void esn_scan(const float* __restrict__ x, const float* __restrict__ Win,
              const float* __restrict__ Wres, const float* __restrict__ Wout,
              float* __restrict__ out, unsigned int* __restrict__ cnt,
              float* __restrict__ rbuf)
{
  const int wg  = blockIdx.x;
  const int g   = wg & 7;    // group
  const int m   = wg >> 3;   // member 0..31
  const int tid = threadIdx.x;
  const int w   = tid >> 6;  // wave 0..7
  const int l   = tid & 63;  // lane

  __shared__ float r_lds[CPG][NR];         // 16 KB: full r_{t-1}, 4 chains
  __shared__ float x_lds[3][CPG][NI + 1];  // mod-3 ring: x[t-1], x[t], x[t+1]
  __shared__ float win_s[WROWS][NI + 1];   // 8.1 KB
  __shared__ float wout_s[NO][WOC];        // 34.8 KB: FULL W_out
  __shared__ float pad_lds[5120];          // 20 KB: static occupancy shaping
                                           // total static ~82.8 KB -> 1 WG/CU

  // runtime-opaque guard (never true for this input): pad_lds is both
  // written AND read -> cannot be DCE'd, allocation is real.
  if (x[0] == 1234.5678f) {
    pad_lds[tid] = Win[tid & 63];
    __syncthreads();
    out[tid] = pad_lds[(tid * 7) & 4095];
  }

  // ---- startup: W_res slice -> AGPRs (64/thread, pinned) ----
  // layout: wa[(r*4+s)*4+e] = W_res[32m+4w+r][4l+256s+e]
  float wa[64];
  {
    const int grow0 = 32 * m + 4 * w;
    #pragma unroll
    for (int r = 0; r < 4; ++r)
      #pragma unroll
      for (int s = 0; s < 4; ++s) {
        float4 t4 = *(const float4*)&Wres[(size_t)(grow0 + r) * NR + 4 * l + 256 * s];
        asm volatile("v_accvgpr_write_b32 %0, %1" : "=a"(wa[(r * 4 + s) * 4 + 0]) : "v"(t4.x));
        asm volatile("v_accvgpr_write_b32 %0, %1" : "=a"(wa[(r * 4 + s) * 4 + 1]) : "v"(t4.y));
        asm volatile("v_accvgpr_write_b32 %0, %1" : "=a"(wa[(r * 4 + s) * 4 + 2]) : "v"(t4.z));
        asm volatile("v_accvgpr_write_b32 %0, %1" : "=a"(wa[(r * 4 + s) * 4 + 3]) : "v"(t4.w));
      }
  }
  for (int idx = tid; idx < WROWS * NI; idx += NT) {
    int rr = idx >> 6, ii = idx & 63;
    win_s[rr][ii] = Win[(32 * m + rr) * NI + ii];
  }
  for (int idx = tid; idx < NO * (NI + NR); idx += NT) {
    int o = idx / (NI + NR), f = idx % (NI + NR);
    wout_s[o][f] = Wout[o * (NI + NR) + f];
  }
  if (tid < 256) {  // x[0] into ring slot 0
    const int c = tid >> 6, ii = tid & 63;
    x_lds[0][c][ii] = x[(size_t)(4 * g + c) * NS * NI + ii];
  }
  __syncthreads();

  unsigned int* bcp = cnt + g * 64;  // barrier counter (256 B apart per group)

  for (int t = 0; t < NS; ++t) {
    const int par = t & 1, pprev = par ^ 1;

    // ---- Phase L: gather r_{t-1} (relaxed agent loads -> LDS) ----
    if (t > 0) {
      const float* rp = rbuf + (size_t)pprev * NB * NR + (size_t)(4 * g) * NR;
      float tv[8];
      #pragma unroll
      for (int j = 0; j < 8; ++j) tv[j] = ATLF(rp + tid + 512 * j);
      #pragma unroll
      for (int j = 0; j < 8; ++j) ((float*)r_lds)[tid + 512 * j] = tv[j];
    } else {
      for (int idx = tid; idx < CPG * NR; idx += NT) ((float*)r_lds)[idx] = 0.f;
    }
    __syncthreads();

    // ---- dot: acc[r][c]; weights streamed from AGPRs ----
    float acc[4][4];
    #pragma unroll
    for (int r = 0; r < 4; ++r)
      #pragma unroll
      for (int c = 0; c < 4; ++c) acc[r][c] = 0.f;
    #pragma unroll
    for (int s = 0; s < 4; ++s) {
      float fa[4][4];
      #pragma unroll
      for (int c = 0; c < 4; ++c) {
        float4 fv = *(const float4*)&r_lds[c][4 * l + 256 * s];
        fa[c][0] = fv.x; fa[c][1] = fv.y; fa[c][2] = fv.z; fa[c][3] = fv.w;
      }
      #pragma unroll
      for (int r = 0; r < 4; ++r) {
        #pragma unroll
        for (int e = 0; e < 4; ++e) {
          float wv;
          asm("v_accvgpr_read_b32 %0, %1" : "=v"(wv) : "a"(wa[(r * 4 + s) * 4 + e]));
          #pragma unroll
          for (int c = 0; c < 4; ++c)
            acc[r][c] = fmaf(wv, fa[c][e], acc[r][c]);
        }
      }
    }

    // ---- paired butterfly: 16 sums across 64 lanes ----
    float v[16];
    #pragma unroll
    for (int k = 0; k < 16; ++k) v[k] = acc[k >> 2][k & 3];
    #pragma unroll
    for (int lev = 0; lev < 4; ++lev) {
      const int d = 1 << lev;
      const int n = 16 >> lev;
      #pragma unroll
      for (int i = 0; i < n / 2; ++i) {
        float a  = v[2 * i]     + __shfl_xor(v[2 * i],     d);
        float bb = v[2 * i + 1] + __shfl_xor(v[2 * i + 1], d);
        v[i] = (l & d) ? bb : a;
      }
    }
    float dsum = v[0];
    dsum += __shfl_xor(dsum, 16);
    dsum += __shfl_xor(dsum, 32);

    // ---- finalize: pin + tanh + relaxed agent store ----
    if (l < 16) {
      const int r = l >> 2, c = l & 3;
      const int lrow = 4 * w + r;
      const int grow = 32 * m + lrow;
      float pin = 0.f;
      #pragma unroll
      for (int ii = 0; ii < NI; ++ii)
        pin = fmaf(win_s[lrow][ii], x_lds[t % 3][c][ii], pin);
      float rv = tanhf(dsum + pin);
      ATSF(rbuf + (size_t)par * NB * NR + (size_t)(4 * g + c) * NR + grow, rv);
    }

    // ---- arrive (early): stores drained by the barrier's vmcnt(0) ----
    __syncthreads();
    if (tid == 0)
      __hip_atomic_fetch_add(bcp, 1u, __ATOMIC_RELAXED, __HIP_MEMORY_SCOPE_AGENT);

    // ---- shadow work while the group converges ----
    if (t + 1 < NS && tid < 256) {
      const int c = tid >> 6, ii = tid & 63;
      x_lds[(t + 1) % 3][c][ii] = x[((size_t)(4 * g + c) * NS + (t + 1)) * NI + ii];
    }
    if (t > 0 && m == ((t - 1) & 31)) {
      const int grp = tid >> 4;   // 0..31 -> (c,o)
      const int j   = tid & 15;
      const int c   = grp >> 3, o = grp & 7;
      float s = 0.f;
      #pragma unroll
      for (int k = 0; k < 16; ++k) {
        const int fb = 64 * k + 4 * j;
        float4 rr = *(const float4*)&r_lds[c][fb];
        float4 ww = *(const float4*)&wout_s[o][NI + fb];
        s = fmaf(ww.x, rr.x, s); s = fmaf(ww.y, rr.y, s);
        s = fmaf(ww.z, rr.z, s); s = fmaf(ww.w, rr.w, s);
      }
      #pragma unroll
      for (int e = 0; e < 4; ++e)
        s = fmaf(wout_s[o][4 * j + e], x_lds[(t + 2) % 3][c][4 * j + e], s);
      s += __shfl_xor(s, 1); s += __shfl_xor(s, 2);
      s += __shfl_xor(s, 4); s += __shfl_xor(s, 8);
      if (j == 0) out[((size_t)(4 * g + c) * NS + (t - 1)) * NO + o] = s;
    }

    // ---- wait (late) ----
    if (tid == 0) {
      const unsigned target = (unsigned)(GPP * (t + 1));
      while (ATLU(bcp) < target) { }
    }
    __syncthreads();
  }

  // ---- final output row t = NS-1 (one WG per group) ----
  if (m == 31) {
    const int fpar = (NS - 1) & 1;
    const float* rp = rbuf + (size_t)fpar * NB * NR + (size_t)(4 * g) * NR;
    float tv[8];
    #pragma unroll
    for (int j = 0; j < 8; ++j) tv[j] = ATLF(rp + tid + 512 * j);
    #pragma unroll
    for (int j = 0; j < 8; ++j) ((float*)r_lds)[tid + 512 * j] = tv[j];
    __syncthreads();
    const int grp = tid >> 4;
    const int j   = tid & 15;
    const int c   = grp >> 3, o = grp & 7;
    float s = 0.f;
    #pragma unroll
    for (int k = 0; k < 16; ++k) {
      const int fb = 64 * k + 4 * j;
      float4 rr = *(const float4*)&r_lds[c][fb];
      float4 ww = *(const float4*)&wout_s[o][NI + fb];
      s = fmaf(ww.x, rr.x, s); s = fmaf(ww.y, rr.y, s);
      s = fmaf(ww.z, rr.z, s); s = fmaf(ww.w, rr.w, s);
    }
    #pragma unroll
    for (int e = 0; e < 4; ++e)
      s = fmaf(wout_s[o][4 * j + e], x_lds[(NS - 1) % 3][c][4 * j + e], s);
    s += __shfl_xor(s, 1); s += __shfl_xor(s, 2);
    s += __shfl_xor(s, 4); s += __shfl_xor(s, 8);
    if (j == 0) out[((size_t)(4 * g + c) * NS + (NS - 1)) * NO + o] = s;
  }
}

extern "C" void kernel_launch(void* const* d_in, const int* in_sizes, int n_in,
                              void* d_out, int out_size, void* d_ws, size_t ws_size,
                              hipStream_t stream) {
  const float* x    = (const float*)d_in[0];
  const float* Win  = (const float*)d_in[1];
  const float* Wres = (const float*)d_in[2];
  const float* Wout = (const float*)d_in[3];
  float* out = (float*)d_out;

  char* ws = (char*)d_ws;
  unsigned int* cnt = (unsigned int*)ws;      // 4 KB barrier counters
  float* rbuf = (float*)(ws + 4096);          // 2*32*1024*4 = 256 KB

  hipLaunchKernelGGL(init_cnt_kernel, dim3(1), dim3(1024), 0, stream, cnt);
  hipLaunchKernelGGL(esn_scan, dim3(256), dim3(NT), 0, stream,
                     x, Win, Wres, Wout, out, cnt, rbuf);
}